// Round 5
// baseline (2111.716 us; speedup 1.0000x reference)
//
#include <hip/hip_runtime.h>
#include <hip/hip_bf16.h>
#include <stdint.h>

#define SEQ    1024
#define NBAT   8
#define EMB    768
#define NHEAD  12
#define MROWS  (NBAT*SEQ)            // 8192
#define SCALE_S 0.03608439182435161f // 1/sqrt(768)

typedef unsigned short u16;
typedef __attribute__((ext_vector_type(8))) short bf16x8;
typedef __attribute__((ext_vector_type(4))) float f32x4;

typedef void __attribute__((address_space(1)))* gas_ptr;
typedef void __attribute__((address_space(3)))* las_ptr;

__device__ __forceinline__ void gload16(const void* g, void* l) {
  __builtin_amdgcn_global_load_lds((gas_ptr)(void*)g, (las_ptr)l, 16, 0, 0);
}

#define VMCNT0 asm volatile("s_waitcnt vmcnt(0)" ::: "memory")
#define VMCNT2 asm volatile("s_waitcnt vmcnt(2)" ::: "memory")
#define VMCNT4 asm volatile("s_waitcnt vmcnt(4)" ::: "memory")
#define VMCNT8 asm volatile("s_waitcnt vmcnt(8)" ::: "memory")
#define LGKM0  asm volatile("s_waitcnt lgkmcnt(0)" ::: "memory")
#define BARRIER asm volatile("s_barrier" ::: "memory")

__device__ __forceinline__ u16 f2bf(float f) {
  union { float f; uint32_t u; } a; a.f = f;
  uint32_t r = a.u + 0x7fffu + ((a.u >> 16) & 1u);
  return (u16)(r >> 16);
}
__device__ __forceinline__ uint32_t pack2(float a, float b) {
  return (uint32_t)f2bf(a) | ((uint32_t)f2bf(b) << 16);
}

// ---------------- conversion kernels ----------------
__global__ void k_cvt(const float* __restrict__ s, u16* __restrict__ d, long n) {
  long i = ((long)blockIdx.x*blockDim.x + threadIdx.x)*8;
  if (i >= n) return;
  float4 a = *(const float4*)(s+i);
  float4 b = *(const float4*)(s+i+4);
  uint4 o; o.x = pack2(a.x,a.y); o.y = pack2(a.z,a.w);
  o.z = pack2(b.x,b.y); o.w = pack2(b.z,b.w);
  *(uint4*)(d+i) = o;
}

__global__ void k_cvt3(const float* __restrict__ s0, const float* __restrict__ s1,
                       const float* __restrict__ s2, u16* __restrict__ d0,
                       u16* __restrict__ d1, u16* __restrict__ d2, long n) {
  const float* s = blockIdx.z == 0 ? s0 : (blockIdx.z == 1 ? s1 : s2);
  u16* d = blockIdx.z == 0 ? d0 : (blockIdx.z == 1 ? d1 : d2);
  long i = ((long)blockIdx.x*blockDim.x + threadIdx.x)*8;
  if (i >= n) return;
  float4 a = *(const float4*)(s+i);
  float4 b = *(const float4*)(s+i+4);
  uint4 o; o.x = pack2(a.x,a.y); o.y = pack2(a.z,a.w);
  o.z = pack2(b.x,b.y); o.w = pack2(b.z,b.w);
  *(uint4*)(d+i) = o;
}

// gather head-slice of Wc [768, 9216] -> wcb [768, Gi*768] bf16
__global__ void k_cvtwc(const float* __restrict__ wc, u16* __restrict__ d, int Gi, int h0) {
  long ncol = (long)Gi*EMB;
  long i = ((long)blockIdx.x*blockDim.x + threadIdx.x)*4;
  if (i >= 768*ncol) return;
  long eo = i / ncol, c = i - eo*ncol;
  long g = c / EMB, dd = c - g*EMB;
  const float* s = wc + eo*(long)(NHEAD*EMB) + (h0+g)*EMB + dd;
  float4 a = *(const float4*)s;
  uint2 o; o.x = pack2(a.x,a.y); o.y = pack2(a.z,a.w);
  *(uint2*)(d+i) = o;
}

// ---------------- 256x256 NT GEMM: C[M,N] = A[M,K]*B[N,K]^T, BK=64, 8 waves ----------------
__global__ __launch_bounds__(512, 2) void k_gemm256(
    const u16* __restrict__ A, int lda,
    const u16* __restrict__ B, int ldb, int K,
    u16* __restrict__ Cb, long c_hs, int ldc,
    const float* __restrict__ bias, const float* __restrict__ bias2,
    int gsplit, int mode)
{
  __shared__ u16 lsA[2*16384];
  __shared__ u16 lsB[2*16384];

  int m0 = blockIdx.x * 256;
  int n0 = blockIdx.y * 256;
  int tid = threadIdx.x;
  int w = tid >> 6, l = tid & 63;
  int wr = w >> 2, wc = w & 3;

  const u16* gA = A + (size_t)(m0 + 32*w + (l>>3))*lda + (((l&7) ^ (l>>3)) << 3);
  const u16* gB = B + (size_t)(n0 + 32*w + (l>>3))*ldb + (((l&7) ^ (l>>3)) << 3);

#define STAGE256(t, buf) do { \
    int k0_ = (t)*64; \
    _Pragma("unroll") \
    for (int c_ = 0; c_ < 4; ++c_) \
      gload16(gA + (size_t)(c_*8)*lda + k0_, lsA + (buf)*16384 + (32*w + 8*c_)*64); \
    _Pragma("unroll") \
    for (int c_ = 0; c_ < 4; ++c_) \
      gload16(gB + (size_t)(c_*8)*ldb + k0_, lsB + (buf)*16384 + (32*w + 8*c_)*64); \
  } while(0)

  f32x4 acc[8][4];
  #pragma unroll
  for (int i = 0; i < 8; ++i)
    #pragma unroll
    for (int j = 0; j < 4; ++j) acc[i][j] = (f32x4)0.0f;

  int nt = K >> 6;
  STAGE256(0, 0);
  for (int t = 0; t < nt; ++t) {
    VMCNT0; BARRIER;
    if (t + 1 < nt) STAGE256(t+1, (t+1)&1);
    const u16* la = lsA + (t&1)*16384;
    const u16* lb = lsB + (t&1)*16384;
    #pragma unroll
    for (int ks = 0; ks < 2; ++ks) {
      int off = (((4*ks + (l>>4)) ^ (l&7)) << 3);
      bf16x8 af[8], bf_[4];
      #pragma unroll
      for (int fi = 0; fi < 8; ++fi)
        af[fi] = *(const bf16x8*)(la + (wr*128 + fi*16 + (l&15))*64 + off);
      #pragma unroll
      for (int fj = 0; fj < 4; ++fj)
        bf_[fj] = *(const bf16x8*)(lb + (wc*64 + fj*16 + (l&15))*64 + off);
      __builtin_amdgcn_s_setprio(1);
      #pragma unroll
      for (int fi = 0; fi < 8; ++fi)
        #pragma unroll
        for (int fj = 0; fj < 4; ++fj)
          acc[fi][fj] = __builtin_amdgcn_mfma_f32_16x16x32_bf16(af[fi], bf_[fj], acc[fi][fj], 0, 0, 0);
      __builtin_amdgcn_s_setprio(0);
    }
  }
#undef STAGE256

  if (mode == 0) {
    int s = n0 / 768;
    int dbase = n0 - s*768 + wc*64;
    const float* bsl = (s < gsplit) ? bias + (size_t)s*768 : bias2 + (size_t)(s - gsplit)*768;
    u16* Cs = Cb + (size_t)s*c_hs;
    #pragma unroll
    for (int fj = 0; fj < 4; ++fj) {
      int dcol = dbase + fj*16 + (l&15);
      float bb = bsl[dcol];
      #pragma unroll
      for (int fi = 0; fi < 8; ++fi) {
        #pragma unroll
        for (int r = 0; r < 4; ++r) {
          int row = m0 + wr*128 + fi*16 + (l>>4)*4 + r;
          Cs[(size_t)row*768 + dcol] = f2bf(acc[fi][fj][r] + bb);
        }
      }
    }
  } else {
    #pragma unroll
    for (int fi = 0; fi < 8; ++fi) {
      #pragma unroll
      for (int r = 0; r < 4; ++r) {
        int row = m0 + wr*128 + fi*16 + (l>>4)*4 + r;
        float bb = bias[row];
        #pragma unroll
        for (int fj = 0; fj < 4; ++fj) {
          int cbn = n0 + wc*64 + fj*16 + (l&15);
          Cb[(size_t)row*ldc + cbn] = f2bf(acc[fi][fj][r] + bb);
        }
      }
    }
  }
}

// ---------------- NT GEMM: 128x128 tile (output projection) ----------------
__global__ __launch_bounds__(256) void k_gemm(
    const u16* __restrict__ A, long a_hs, int lda,
    const u16* __restrict__ B, long b_hs, int ldb, int K,
    u16* Cb, float* Cf, long c_hs, int ldc,
    const float* __restrict__ bias, const float* __restrict__ bias2,
    long bias_hs, int gsplit, int mode, int swapxy)
{
  __shared__ u16 lsA[3*4096];
  __shared__ u16 lsB[3*4096];
  int g = blockIdx.z;
  const u16* Ag = A + (long)g*a_hs;
  const u16* Bg = B + (long)g*b_hs;
  int tm = swapxy ? blockIdx.y : blockIdx.x;
  int tn = swapxy ? blockIdx.x : blockIdx.y;
  int m0 = tm*128, n0 = tn*128;
  int tid = threadIdx.x;
  int w = tid >> 6, l = tid & 63;

  int srow = l >> 2;
  int scol = ((l & 3) ^ ((l >> 3) & 3)) * 8;
  const u16* ga0 = Ag + (long)(m0 + (2*w)*16   + srow)*lda + scol;
  const u16* ga1 = Ag + (long)(m0 + (2*w+1)*16 + srow)*lda + scol;
  const u16* gb0 = Bg + (long)(n0 + (2*w)*16   + srow)*ldb + scol;
  const u16* gb1 = Bg + (long)(n0 + (2*w+1)*16 + srow)*ldb + scol;

#define GSTAGE(k0, buf) do { \
    gload16(ga0 + (k0), lsA + (buf)*4096 + (2*w)*512); \
    gload16(ga1 + (k0), lsA + (buf)*4096 + (2*w+1)*512); \
    gload16(gb0 + (k0), lsB + (buf)*4096 + (2*w)*512); \
    gload16(gb1 + (k0), lsB + (buf)*4096 + (2*w+1)*512); \
  } while(0)

  f32x4 acc[4][4];
  #pragma unroll
  for (int i = 0; i < 4; ++i)
    #pragma unroll
    for (int j = 0; j < 4; ++j) acc[i][j] = (f32x4)0.0f;

  int wr = w >> 1, wc_ = w & 1;
  int frow = l & 15;
  int sp = (l >> 4) ^ ((frow >> 1) & 3);
  int aoff[4], boff[4];
  #pragma unroll
  for (int i = 0; i < 4; ++i) {
    aoff[i] = (wr*64 + i*16 + frow)*32 + sp*8;
    boff[i] = (wc_*64 + i*16 + frow)*32 + sp*8;
  }

  int nt = K >> 5;
  GSTAGE(0, 0);
  GSTAGE(32, 1);
  VMCNT4; BARRIER;
  int cur = 0;
  for (int t = 0; t < nt; ++t) {
    if (t + 2 < nt) {
      int nb = cur + 2; if (nb >= 3) nb -= 3;
      GSTAGE((t+2) << 5, nb);
    }
    const u16* la = lsA + cur*4096;
    const u16* lb = lsB + cur*4096;
    bf16x8 af[4], bfr[4];
    #pragma unroll
    for (int i = 0; i < 4; ++i) af[i] = *(const bf16x8*)(la + aoff[i]);
    #pragma unroll
    for (int j = 0; j < 4; ++j) bfr[j] = *(const bf16x8*)(lb + boff[j]);
    #pragma unroll
    for (int i = 0; i < 4; ++i)
      #pragma unroll
      for (int j = 0; j < 4; ++j)
        acc[i][j] = __builtin_amdgcn_mfma_f32_16x16x32_bf16(af[i], bfr[j], acc[i][j], 0, 0, 0);
    if (t + 2 < nt) { VMCNT4; } else { VMCNT0; }
    LGKM0; BARRIER;
    cur = (cur == 2) ? 0 : cur + 1;
  }
#undef GSTAGE

  u16* Cbg = Cb ? Cb + (long)g*c_hs : (u16*)0;
  const float* bsel = (g < gsplit) ? bias : bias2;
  long gi = (g < gsplit) ? g : g - gsplit;
  const float* bs = bsel ? bsel + gi*bias_hs : (const float*)0;
  int rl = (l >> 4)*4, cl = l & 15;
  #pragma unroll
  for (int i = 0; i < 4; ++i) {
    #pragma unroll
    for (int j = 0; j < 4; ++j) {
      int rb = m0 + wr*64 + i*16 + rl;
      int cb = n0 + wc_*64 + j*16 + cl;
      float cbv = 0.f;
      if ((mode == 0 || mode == 2) && bs) cbv = bs[cb];
      #pragma unroll
      for (int r = 0; r < 4; ++r) {
        int rr = rb + r;
        float v = acc[i][j][r];
        v += (mode == 1) ? bs[rr] : cbv;
        size_t idx = (size_t)rr*(size_t)ldc + cb;
        if (mode <= 1) Cbg[idx] = f2bf(v);
        else if (mode == 2) Cf[idx] = v;
        else Cf[idx] += v;
      }
    }
  }
}

// ---------------- flash attention (causal), QBLK=64, KBLK=64, 8 waves ----------------
// Swapped QK^T (S^T via mfma(K,Q)), in-register softmax, P-in-reg PV (O^T = V^T * P^T).
// Shared 3x32KB chunk pool time-shared K/V, e-chunks of 256, uniform vmcnt(4) schedule.
__global__ __launch_bounds__(512, 2) void k_attn(
    const u16* __restrict__ qb, const u16* __restrict__ kb,
    const u16* __restrict__ vtb, u16* __restrict__ hb, int ldh)
{
  __shared__ u16 pool[3*16384];   // 3 bufs x 32KB: [64 rows][256 e] (K/Q) or [256 e][64 t] (V)
  __shared__ u16 p_t[64*64];      // P[q][kv], 16B-slot swizzled by (q&7)
  __shared__ float st_mx[128];    // [khalf][q] partial max
  __shared__ float st_sm[128];    // [khalf][q] partial sum
  __shared__ float e_sc[64];      // esc per q
  __shared__ float e_li[64];      // 1/l per q

  int b = blockIdx.x;
  int xcd = b & 7, kk_ = b >> 3;
  int gn = xcd + 8*(kk_ >> 3), pair = kk_ & 7;
  int g = gn >> 3, n = gn & 7;

  const u16* Q  = qb  + (size_t)g*MROWS*EMB + (size_t)n*SEQ*EMB;
  const u16* Kp = kb  + (size_t)g*MROWS*EMB + (size_t)n*SEQ*EMB;
  const u16* Vt = vtb + (size_t)g*EMB*MROWS + (size_t)n*SEQ;
  u16* H = hb + (size_t)(n*SEQ)*ldh + (size_t)g*EMB;

  int tid = threadIdx.x;
  int w = tid >> 6, l = tid & 63;
  int lo = l & 15, hi = l >> 4;
  int khalf = w >> 2;             // kv 32-half owner (QK role)
  int qbase = (w & 3) * 16;       // q16 group (QK role)
  int myq = qbase + lo;           // lane's q row (QK role)
  int kv0 = khalf*32 + lo;        // A-frag row, kf=0
  int kv1 = kv0 + 16;             // A-frag row, kf=1

  // stage one 32KB chunk: 2048 16B units, unit u = tid + 512*i
#define KSTAGE(base, ch, buf) do { \
    _Pragma("unroll") for (int i_ = 0; i_ < 4; ++i_) { \
      int u_ = tid + 512*i_; \
      gload16((base) + (size_t)(u_>>5)*EMB + ((ch)*256 + (((u_&31) ^ ((u_>>5)&31))<<3)), \
              pool + (buf)*16384 + ((w*64 + 512*i_)<<3)); \
    } } while(0)
#define VSTAGE(t0v, ch, buf) do { \
    _Pragma("unroll") for (int i_ = 0; i_ < 4; ++i_) { \
      int u_ = tid + 512*i_; \
      gload16(Vt + (size_t)((ch)*256 + (u_>>3))*MROWS + (t0v) + (((u_&7) ^ ((u_>>3)&7))<<3), \
              pool + (buf)*16384 + ((w*64 + 512*i_)<<3)); \
    } } while(0)

#define QK_COMPUTE(ch) do { \
    const u16* kb_ = pool + (ch)*16384; \
    __builtin_amdgcn_s_setprio(1); \
    _Pragma("unroll") for (int ks = 0; ks < 8; ++ks) { \
      bf16x8 k0_ = *(const bf16x8*)(kb_ + ((kv0*32 + ((ks*4 + hi) ^ (kv0 & 31)))<<3)); \
      bf16x8 k1_ = *(const bf16x8*)(kb_ + ((kv1*32 + ((ks*4 + hi) ^ (kv1 & 31)))<<3)); \
      sacc0 = __builtin_amdgcn_mfma_f32_16x16x32_bf16(k0_, qreg[(ch)*8+ks], sacc0, 0, 0, 0); \
      sacc1 = __builtin_amdgcn_mfma_f32_16x16x32_bf16(k1_, qreg[(ch)*8+ks], sacc1, 0, 0, 0); \
    } \
    __builtin_amdgcn_s_setprio(0); \
  } while(0)

#define PV_COMPUTE(ch) do { \
    const u16* vb_ = pool + (ch)*16384; \
    __builtin_amdgcn_s_setprio(1); \
    _Pragma("unroll") for (int jp = 0; jp < 2; ++jp) { \
      int el_ = (w + 8*jp)*16 + lo; \
      _Pragma("unroll") for (int ks2 = 0; ks2 < 2; ++ks2) { \
        bf16x8 vf_ = *(const bf16x8*)(vb_ + (((el_<<3) + ((ks2*4 + hi) ^ (el_ & 7)))<<3)); \
        _Pragma("unroll") for (int qf = 0; qf < 4; ++qf) \
          acc[2*(ch)+jp][qf] = __builtin_amdgcn_mfma_f32_16x16x32_bf16(vf_, pf[ks2][qf], acc[2*(ch)+jp][qf], 0, 0, 0); \
      } \
    } \
    __builtin_amdgcn_s_setprio(0); \
  } while(0)

  for (int half = 0; half < 2; ++half) {
    int qt = half ? 15 - pair : pair;
    int q0 = qt * 64;
    int nt = qt + 1;
    int qabs = q0 + myq;

    f32x4 acc[6][4];
    #pragma unroll
    for (int i = 0; i < 6; ++i)
      #pragma unroll
      for (int j = 0; j < 4; ++j) acc[i][j] = (f32x4)0.0f;
    float m_reg = -1e30f, l_reg = 0.f;

    // ---- Q-pass prologue: Q (B-layout) -> qreg[24] ----
    const u16* Qb = Q + (size_t)q0*EMB;
    VMCNT0;                       // drain dangling dummy staging from previous half
    KSTAGE(Qb, 0, 0);
    KSTAGE(Qb, 1, 1);
    KSTAGE(Qb, 2, 2);
    VMCNT8; BARRIER;
    bf16x8 qreg[24];
    // p0
    #pragma unroll
    for (int ks = 0; ks < 8; ++ks)
      qreg[ks] = *(const bf16x8*)(pool + ((myq*32 + ((ks*4 + hi) ^ (myq & 31)))<<3));
    VMCNT4; LGKM0; BARRIER;
    // p1
    KSTAGE(Kp, 0, 0);
    #pragma unroll
    for (int ks = 0; ks < 8; ++ks)
      qreg[8+ks] = *(const bf16x8*)(pool + 16384 + ((myq*32 + ((ks*4 + hi) ^ (myq & 31)))<<3));
    VMCNT4; LGKM0; BARRIER;
    // p2
    KSTAGE(Kp, 1, 1);
    #pragma unroll
    for (int ks = 0; ks < 8; ++ks)
      qreg[16+ks] = *(const bf16x8*)(pool + 2*16384 + ((myq*32 + ((ks*4 + hi) ^ (myq & 31)))<<3));
    VMCNT4; LGKM0; BARRIER;

    for (int tt = 0; tt < nt; ++tt) {
      int t0 = tt*64;
      int nt0 = (tt + 1 < nt) ? (tt+1)*64 : 0;   // clamped next tile (dummy keeps vmcnt uniform)
      f32x4 sacc0 = (f32x4)0.0f, sacc1 = (f32x4)0.0f;

      // ---- QK: 3 phases of e-chunk 256 ----
      KSTAGE(Kp + (size_t)t0*EMB, 2, 2);          // K2 (this tile)
      QK_COMPUTE(0);
      VMCNT4; LGKM0; BARRIER;
      VSTAGE(t0, 0, 0);                            // V0
      QK_COMPUTE(1);
      VMCNT4; LGKM0; BARRIER;
      VSTAGE(t0, 1, 1);                            // V1
      QK_COMPUTE(2);
      VMCNT4; LGKM0; BARRIER;

      // ---- softmax (in-register) ----
      VSTAGE(t0, 2, 2);                            // V2
      float pm = -1e30f;
      {
        int kvb = t0 + khalf*32 + hi*4;
        #pragma unroll
        for (int r = 0; r < 4; ++r) {
          float x0 = sacc0[r]*SCALE_S;
          float x1 = sacc1[r]*SCALE_S;
          if (kvb + r > qabs)      x0 = -1e30f;
          if (kvb + 16 + r > qabs) x1 = -1e30f;
          sacc0[r] = x0; sacc1[r] = x1;
          pm = fmaxf(pm, fmaxf(x0, x1));
        }
      }
      pm = fmaxf(pm, __shfl_xor(pm, 16));
      pm = fmaxf(pm, __shfl_xor(pm, 32));
      if (l < 16) st_mx[khalf*64 + myq] = pm;
      LGKM0; BARRIER;   // sm1
      float mn = fmaxf(m_reg, fmaxf(st_mx[myq], st_mx[64 + myq]));
      float esc = __expf(m_reg - mn);
      m_reg = mn;
      float p0_ = __expf(sacc0[0]-mn), p1_ = __expf(sacc0[1]-mn);
      float p2_ = __expf(sacc0[2]-mn), p3_ = __expf(sacc0[3]-mn);
      float p4_ = __expf(sacc1[0]-mn), p5_ = __expf(sacc1[1]-mn);
      float p6_ = __expf(sacc1[2]-mn), p7_ = __expf(sacc1[3]-mn);
      float ps = ((p0_+p1_)+(p2_+p3_)) + ((p4_+p5_)+(p6_+p7_));
      ps += __shfl_xor(ps, 16);
      ps += __shfl_xor(ps, 32);
      if (l < 16) { st_sm[khalf*64 + myq] = ps; if (khalf == 0) e_sc[myq] = esc; }
      {
        int sl0 = khalf*4 + (hi>>1);
        int ph0 = sl0 ^ (myq & 7);
        int ph1 = (sl0 + 2) ^ (myq & 7);
        uint2 v0; v0.x = pack2(p0_, p1_); v0.y = pack2(p2_, p3_);
        uint2 v1; v1.x = pack2(p4_, p5_); v1.y = pack2(p6_, p7_);
        *(uint2*)(p_t + myq*64 + ph0*8 + (hi&1)*4) = v0;
        *(uint2*)(p_t + myq*64 + ph1*8 + (hi&1)*4) = v1;
      }
      LGKM0; BARRIER;   // sm2
      l_reg = l_reg*esc + st_sm[myq] + st_sm[64 + myq];

      // ---- P fragments (B-layout, in-reg) + acc rescale ----
      bf16x8 pf[2][4];
      #pragma unroll
      for (int ks2 = 0; ks2 < 2; ++ks2)
        #pragma unroll
        for (int qf = 0; qf < 4; ++qf) {
          int qr = qf*16 + lo;
          pf[ks2][qf] = *(const bf16x8*)(p_t + ((qr*8 + ((ks2*4 + hi) ^ (qr & 7)))<<3));
        }
      float escq[4];
      #pragma unroll
      for (int qf = 0; qf < 4; ++qf) escq[qf] = e_sc[qf*16 + lo];
      #pragma unroll
      for (int i = 0; i < 6; ++i)
        #pragma unroll
        for (int qf = 0; qf < 4; ++qf)
          #pragma unroll
          for (int r = 0; r < 4; ++r) acc[i][qf][r] *= escq[qf];

      // ---- PV: 3 phases ----
      PV_COMPUTE(0);
      VMCNT4; LGKM0; BARRIER;
      KSTAGE(Kp + (size_t)nt0*EMB, 0, 0);          // K'0
      PV_COMPUTE(1);
      VMCNT4; LGKM0; BARRIER;
      KSTAGE(Kp + (size_t)nt0*EMB, 1, 1);          // K'1
      PV_COMPUTE(2);
      VMCNT4; LGKM0; BARRIER;
    } // tt

    // ---- epilogue: O^T -> H ----
    if (l < 16 && khalf == 0) e_li[myq] = 1.0f / l_reg;
    LGKM0; BARRIER;
    float li[4];
    #pragma unroll
    for (int qf = 0; qf < 4; ++qf) li[qf] = e_li[qf*16 + lo];
    #pragma unroll
    for (int j = 0; j < 6; ++j) {
      int e_g = (j>>1)*256 + (w + 8*(j&1))*16 + hi*4;
      #pragma unroll
      for (int qf = 0; qf < 4; ++qf) {
        int q_abs2 = q0 + qf*16 + lo;
        uint2 v;
        v.x = pack2(acc[j][qf][0]*li[qf], acc[j][qf][1]*li[qf]);
        v.y = pack2(acc[j][qf][2]*li[qf], acc[j][qf][3]*li[qf]);
        *(uint2*)(H + (size_t)q_abs2*ldh + e_g) = v;
      }
    }
    BARRIER;
  } // half
#undef KSTAGE
#undef VSTAGE
#undef QK_COMPUTE
#undef PV_COMPUTE
}

// ---------------- host ----------------
extern "C" void kernel_launch(void* const* d_in, const int* in_sizes, int n_in,
                              void* d_out, int out_size, void* d_ws, size_t ws_size,
                              hipStream_t stream) {
  const float* x  = (const float*)d_in[0];
  const float* Wq = (const float*)d_in[1];
  const float* bq = (const float*)d_in[2];
  const float* Wk = (const float*)d_in[3];
  const float* bk = (const float*)d_in[4];
  const float* Wv = (const float*)d_in[5];
  const float* bv = (const float*)d_in[6];
  const float* Wc = (const float*)d_in[7];
  const float* bc = (const float*)d_in[8];
  float* out = (float*)d_out;

  const size_t XB  = (size_t)MROWS*EMB*sizeof(u16);
  const size_t WHB = (size_t)EMB*EMB*sizeof(u16);
  const size_t per_g = 4*WHB + 4*XB;
  long long avail = (long long)ws_size - (long long)XB - 4096;
  int G = (int)(avail / (long long)per_g);
  if (G < 1) G = 1;
  if (G > NHEAD) G = NHEAD;

  char* ws = (char*)d_ws;
  u16* xb  = (u16*)ws;  ws += XB;
  u16* wqb = (u16*)ws;  ws += (size_t)(2*G)*WHB;
  u16* wvb = (u16*)ws;  ws += (size_t)G*WHB;
  u16* wcb = (u16*)ws;  ws += (size_t)G*WHB;
  u16* qb  = (u16*)ws;  ws += (size_t)(2*G)*XB;
  u16* vtb = (u16*)ws;  ws += (size_t)G*XB;
  u16* hbf = (u16*)ws;  ws += (size_t)G*XB;

  k_cvt<<<dim3(3072), dim3(256), 0, stream>>>(x, xb, (long)MROWS*EMB);

  for (int h0 = 0; h0 < NHEAD; h0 += G) {
    int Gi = (G < NHEAD - h0) ? G : (NHEAD - h0);
    long nw = (long)Gi*EMB*EMB;
    k_cvt3<<<dim3((unsigned)(nw/8/256), 1, 3), dim3(256), 0, stream>>>(
        Wq + (size_t)h0*EMB*EMB, Wk + (size_t)h0*EMB*EMB, Wv + (size_t)h0*EMB*EMB,
        wqb, wqb + (size_t)Gi*EMB*EMB, wvb, nw);
    k_cvtwc<<<dim3((unsigned)((768L*Gi*EMB/4)/256)), dim3(256), 0, stream>>>(Wc, wcb, Gi, h0);
    // fused Q|K projection
    k_gemm256<<<dim3(32, 6*Gi), dim3(512), 0, stream>>>(
        xb, EMB, wqb, EMB, EMB,
        qb, (long)MROWS*EMB, 768,
        bq + (size_t)h0*EMB, bk + (size_t)h0*EMB, Gi, 0);
    // Vt = Wv*x^T + bv
    k_gemm256<<<dim3(3*Gi, 32), dim3(512), 0, stream>>>(
        wvb, EMB, xb, EMB, EMB,
        vtb, 0L, MROWS,
        bv + (size_t)h0*EMB, (const float*)0, 9999, 1);
    // flash attention -> hbf [8192, Gi*768]
    k_attn<<<dim3(8*NBAT*Gi), dim3(512), 0, stream>>>(
        qb, qb + (size_t)Gi*MROWS*EMB, vtb, hbf, Gi*EMB);
    // out += heads_group * Wc_group^T (+bc on first group)
    k_gemm<<<dim3(64, 6, 1), dim3(256), 0, stream>>>(
        hbf, 0L, Gi*EMB, wcb, 0L, Gi*EMB, Gi*EMB,
        (u16*)0, out, 0L, EMB,
        (h0 == 0 ? bc : (const float*)0), (const float*)0, 0L, 9999,
        (h0 == 0 ? 2 : 3), 0);
  }
}

// Round 6
// 1198.027 us; speedup vs baseline: 1.7627x; 1.7627x over previous
//
#include <hip/hip_runtime.h>
#include <hip/hip_bf16.h>
#include <stdint.h>

#define SEQ    1024
#define NBAT   8
#define EMB    768
#define NHEAD  12
#define MROWS  (NBAT*SEQ)            // 8192
#define SCALE_S 0.03608439182435161f // 1/sqrt(768)

typedef unsigned short u16;
typedef __attribute__((ext_vector_type(8))) short bf16x8;
typedef __attribute__((ext_vector_type(4))) float f32x4;

typedef void __attribute__((address_space(1)))* gas_ptr;
typedef void __attribute__((address_space(3)))* las_ptr;

__device__ __forceinline__ void gload16(const void* g, void* l) {
  __builtin_amdgcn_global_load_lds((gas_ptr)(void*)g, (las_ptr)l, 16, 0, 0);
}

#define VMCNT0 asm volatile("s_waitcnt vmcnt(0)" ::: "memory")
#define VMCNT2 asm volatile("s_waitcnt vmcnt(2)" ::: "memory")
#define VMCNT4 asm volatile("s_waitcnt vmcnt(4)" ::: "memory")
#define VMCNT6 asm volatile("s_waitcnt vmcnt(6)" ::: "memory")
#define LGKM0  asm volatile("s_waitcnt lgkmcnt(0)" ::: "memory")
#define BARRIER asm volatile("s_barrier" ::: "memory")

__device__ __forceinline__ u16 f2bf(float f) {
  union { float f; uint32_t u; } a; a.f = f;
  uint32_t r = a.u + 0x7fffu + ((a.u >> 16) & 1u);
  return (u16)(r >> 16);
}
__device__ __forceinline__ uint32_t pack2(float a, float b) {
  return (uint32_t)f2bf(a) | ((uint32_t)f2bf(b) << 16);
}

// ---------------- conversion kernels ----------------
__global__ void k_cvt(const float* __restrict__ s, u16* __restrict__ d, long n) {
  long i = ((long)blockIdx.x*blockDim.x + threadIdx.x)*8;
  if (i >= n) return;
  float4 a = *(const float4*)(s+i);
  float4 b = *(const float4*)(s+i+4);
  uint4 o; o.x = pack2(a.x,a.y); o.y = pack2(a.z,a.w);
  o.z = pack2(b.x,b.y); o.w = pack2(b.z,b.w);
  *(uint4*)(d+i) = o;
}

__global__ void k_cvt3(const float* __restrict__ s0, const float* __restrict__ s1,
                       const float* __restrict__ s2, u16* __restrict__ d0,
                       u16* __restrict__ d1, u16* __restrict__ d2, long n) {
  const float* s = blockIdx.z == 0 ? s0 : (blockIdx.z == 1 ? s1 : s2);
  u16* d = blockIdx.z == 0 ? d0 : (blockIdx.z == 1 ? d1 : d2);
  long i = ((long)blockIdx.x*blockDim.x + threadIdx.x)*8;
  if (i >= n) return;
  float4 a = *(const float4*)(s+i);
  float4 b = *(const float4*)(s+i+4);
  uint4 o; o.x = pack2(a.x,a.y); o.y = pack2(a.z,a.w);
  o.z = pack2(b.x,b.y); o.w = pack2(b.z,b.w);
  *(uint4*)(d+i) = o;
}

// gather head-slice of Wc [768, 9216] -> wcb [768, Gi*768] bf16
__global__ void k_cvtwc(const float* __restrict__ wc, u16* __restrict__ d, int Gi, int h0) {
  long ncol = (long)Gi*EMB;
  long i = ((long)blockIdx.x*blockDim.x + threadIdx.x)*4;
  if (i >= 768*ncol) return;
  long eo = i / ncol, c = i - eo*ncol;
  long g = c / EMB, dd = c - g*EMB;
  const float* s = wc + eo*(long)(NHEAD*EMB) + (h0+g)*EMB + dd;
  float4 a = *(const float4*)s;
  uint2 o; o.x = pack2(a.x,a.y); o.y = pack2(a.z,a.w);
  *(uint2*)(d+i) = o;
}

// ---------------- 256x128 NT GEMM: C[M,N] = A[M,K]*B[N,K]^T, BK=64, 8 waves ----------------
// 3 LDS buffers (144 KB), depth-2 counted-vmcnt pipeline: 6 loads/thread/tile,
// steady-state wait vmcnt(6) (next tile stays in flight), stage t+2 after barrier.
// mode 0: bf16 out, sliced columns (slice width 768, stride c_hs), col-bias split at gsplit.
// mode 1: bf16 out, plain ldc, row-bias.
__global__ __launch_bounds__(512, 2) void k_gemm256(
    const u16* __restrict__ A, int lda,
    const u16* __restrict__ B, int ldb, int K,
    u16* __restrict__ Cb, long c_hs, int ldc,
    const float* __restrict__ bias, const float* __restrict__ bias2,
    int gsplit, int mode)
{
  __shared__ u16 lsA[3*16384];   // 3 bufs x (256 rows x 64 cols)
  __shared__ u16 lsB[3*8192];    // 3 bufs x (128 rows x 64 cols)

  int m0 = blockIdx.x * 256;
  int n0 = blockIdx.y * 128;
  int tid = threadIdx.x;
  int w = tid >> 6, l = tid & 63;
  int wr = w >> 1, wc = w & 1;       // wave tile: rows wr*64, cols wc*64
  int lo = l & 15, hi = l >> 4;

  // staging: chunk = 8 rows x 64 cols (1 KB); lane l -> row l>>3, phys slot l&7
  // holds source col-slot (l&7)^(l>>3).  A: wave w rows 32w..32w+31 (4 chunks);
  // B: wave w rows 16w..16w+15 (2 chunks).
  const u16* gA = A + (size_t)(m0 + 32*w + (l>>3))*lda + (((l&7) ^ (l>>3)) << 3);
  const u16* gB = B + (size_t)(n0 + 16*w + (l>>3))*ldb + (((l&7) ^ (l>>3)) << 3);

#define STAGE256(t, buf) do { \
    int k0_ = (t)*64; \
    _Pragma("unroll") \
    for (int c_ = 0; c_ < 4; ++c_) \
      gload16(gA + (size_t)(c_*8)*lda + k0_, lsA + (buf)*16384 + (32*w + 8*c_)*64); \
    _Pragma("unroll") \
    for (int c_ = 0; c_ < 2; ++c_) \
      gload16(gB + (size_t)(c_*8)*ldb + k0_, lsB + (buf)*8192 + (16*w + 8*c_)*64); \
  } while(0)

  f32x4 acc[4][4];
  #pragma unroll
  for (int i = 0; i < 4; ++i)
    #pragma unroll
    for (int j = 0; j < 4; ++j) acc[i][j] = (f32x4)0.0f;

  int nt = K >> 6;    // assumes nt >= 3
  STAGE256(0, 0);
  STAGE256(1, 1);
  for (int t = 0; t < nt; ++t) {
    if (t + 1 < nt) { VMCNT6; } else { VMCNT0; }
    BARRIER;
    if (t + 2 < nt) {
      int nb = t + 2; nb -= (nb/3)*3;
      STAGE256(t+2, nb);
    }
    int cb = t - (t/3)*3;
    const u16* la = lsA + cb*16384;
    const u16* lb = lsB + cb*8192;
    #pragma unroll
    for (int ks = 0; ks < 2; ++ks) {
      bf16x8 af[4], bf_[4];
      #pragma unroll
      for (int fi = 0; fi < 4; ++fi) {
        int row = wr*64 + fi*16 + lo;
        af[fi] = *(const bf16x8*)(la + row*64 + (((4*ks + hi) ^ (row & 7)) << 3));
      }
      #pragma unroll
      for (int fj = 0; fj < 4; ++fj) {
        int row = wc*64 + fj*16 + lo;
        bf_[fj] = *(const bf16x8*)(lb + row*64 + (((4*ks + hi) ^ (row & 7)) << 3));
      }
      __builtin_amdgcn_s_setprio(1);
      #pragma unroll
      for (int fi = 0; fi < 4; ++fi)
        #pragma unroll
        for (int fj = 0; fj < 4; ++fj)
          acc[fi][fj] = __builtin_amdgcn_mfma_f32_16x16x32_bf16(af[fi], bf_[fj], acc[fi][fj], 0, 0, 0);
      __builtin_amdgcn_s_setprio(0);
    }
  }
#undef STAGE256

  if (mode == 0) {
    int s = n0 / 768;
    int dbase = n0 - s*768 + wc*64;
    const float* bsl = (s < gsplit) ? bias + (size_t)s*768 : bias2 + (size_t)(s - gsplit)*768;
    u16* Cs = Cb + (size_t)s*c_hs;
    #pragma unroll
    for (int fj = 0; fj < 4; ++fj) {
      int dcol = dbase + fj*16 + lo;
      float bb = bsl[dcol];
      #pragma unroll
      for (int fi = 0; fi < 4; ++fi) {
        #pragma unroll
        for (int r = 0; r < 4; ++r) {
          int row = m0 + wr*64 + fi*16 + hi*4 + r;
          Cs[(size_t)row*768 + dcol] = f2bf(acc[fi][fj][r] + bb);
        }
      }
    }
  } else {
    #pragma unroll
    for (int fi = 0; fi < 4; ++fi) {
      #pragma unroll
      for (int r = 0; r < 4; ++r) {
        int row = m0 + wr*64 + fi*16 + hi*4 + r;
        float bb = bias[row];
        #pragma unroll
        for (int fj = 0; fj < 4; ++fj) {
          int cbn = n0 + wc*64 + fj*16 + lo;
          Cb[(size_t)row*ldc + cbn] = f2bf(acc[fi][fj][r] + bb);
        }
      }
    }
  }
}

// ---------------- NT GEMM: 128x128 tile (output projection) ----------------
__global__ __launch_bounds__(256) void k_gemm(
    const u16* __restrict__ A, long a_hs, int lda,
    const u16* __restrict__ B, long b_hs, int ldb, int K,
    u16* Cb, float* Cf, long c_hs, int ldc,
    const float* __restrict__ bias, const float* __restrict__ bias2,
    long bias_hs, int gsplit, int mode, int swapxy)
{
  __shared__ u16 lsA[3*4096];
  __shared__ u16 lsB[3*4096];
  int g = blockIdx.z;
  const u16* Ag = A + (long)g*a_hs;
  const u16* Bg = B + (long)g*b_hs;
  int tm = swapxy ? blockIdx.y : blockIdx.x;
  int tn = swapxy ? blockIdx.x : blockIdx.y;
  int m0 = tm*128, n0 = tn*128;
  int tid = threadIdx.x;
  int w = tid >> 6, l = tid & 63;

  int srow = l >> 2;
  int scol = ((l & 3) ^ ((l >> 3) & 3)) * 8;
  const u16* ga0 = Ag + (long)(m0 + (2*w)*16   + srow)*lda + scol;
  const u16* ga1 = Ag + (long)(m0 + (2*w+1)*16 + srow)*lda + scol;
  const u16* gb0 = Bg + (long)(n0 + (2*w)*16   + srow)*ldb + scol;
  const u16* gb1 = Bg + (long)(n0 + (2*w+1)*16 + srow)*ldb + scol;

#define GSTAGE(k0, buf) do { \
    gload16(ga0 + (k0), lsA + (buf)*4096 + (2*w)*512); \
    gload16(ga1 + (k0), lsA + (buf)*4096 + (2*w+1)*512); \
    gload16(gb0 + (k0), lsB + (buf)*4096 + (2*w)*512); \
    gload16(gb1 + (k0), lsB + (buf)*4096 + (2*w+1)*512); \
  } while(0)

  f32x4 acc[4][4];
  #pragma unroll
  for (int i = 0; i < 4; ++i)
    #pragma unroll
    for (int j = 0; j < 4; ++j) acc[i][j] = (f32x4)0.0f;

  int wr = w >> 1, wc_ = w & 1;
  int frow = l & 15;
  int sp = (l >> 4) ^ ((frow >> 1) & 3);
  int aoff[4], boff[4];
  #pragma unroll
  for (int i = 0; i < 4; ++i) {
    aoff[i] = (wr*64 + i*16 + frow)*32 + sp*8;
    boff[i] = (wc_*64 + i*16 + frow)*32 + sp*8;
  }

  int nt = K >> 5;
  GSTAGE(0, 0);
  GSTAGE(32, 1);
  VMCNT4; BARRIER;
  int cur = 0;
  for (int t = 0; t < nt; ++t) {
    if (t + 2 < nt) {
      int nb = cur + 2; if (nb >= 3) nb -= 3;
      GSTAGE((t+2) << 5, nb);
    }
    const u16* la = lsA + cur*4096;
    const u16* lb = lsB + cur*4096;
    bf16x8 af[4], bfr[4];
    #pragma unroll
    for (int i = 0; i < 4; ++i) af[i] = *(const bf16x8*)(la + aoff[i]);
    #pragma unroll
    for (int j = 0; j < 4; ++j) bfr[j] = *(const bf16x8*)(lb + boff[j]);
    #pragma unroll
    for (int i = 0; i < 4; ++i)
      #pragma unroll
      for (int j = 0; j < 4; ++j)
        acc[i][j] = __builtin_amdgcn_mfma_f32_16x16x32_bf16(af[i], bfr[j], acc[i][j], 0, 0, 0);
    if (t + 2 < nt) { VMCNT4; } else { VMCNT0; }
    LGKM0; BARRIER;
    cur = (cur == 2) ? 0 : cur + 1;
  }
#undef GSTAGE

  u16* Cbg = Cb ? Cb + (long)g*c_hs : (u16*)0;
  const float* bsel = (g < gsplit) ? bias : bias2;
  long gi = (g < gsplit) ? g : g - gsplit;
  const float* bs = bsel ? bsel + gi*bias_hs : (const float*)0;
  int rl = (l >> 4)*4, cl = l & 15;
  #pragma unroll
  for (int i = 0; i < 4; ++i) {
    #pragma unroll
    for (int j = 0; j < 4; ++j) {
      int rb = m0 + wr*64 + i*16 + rl;
      int cb = n0 + wc_*64 + j*16 + cl;
      float cbv = 0.f;
      if ((mode == 0 || mode == 2) && bs) cbv = bs[cb];
      #pragma unroll
      for (int r = 0; r < 4; ++r) {
        int rr = rb + r;
        float v = acc[i][j][r];
        v += (mode == 1) ? bs[rr] : cbv;
        size_t idx = (size_t)rr*(size_t)ldc + cb;
        if (mode <= 1) Cbg[idx] = f2bf(v);
        else if (mode == 2) Cf[idx] = v;
        else Cf[idx] += v;
      }
    }
  }
}

// ---------------- flash attention (causal), QBLK=64, KBLK=64, 8 waves ----------------
// (r4 version: Q held in registers; QK e-chunks of 128; 3-deep pipelines)
__global__ __launch_bounds__(512, 2) void k_attn(
    const u16* __restrict__ qb, const u16* __restrict__ kb,
    const u16* __restrict__ vtb, u16* __restrict__ hb, int ldh)
{
  __shared__ u16 kls[3*8192];
  __shared__ u16 vls[3*8192];
  __shared__ float s_t[64*68];
  __shared__ u16 p_t[64*64];
  __shared__ float e_s[64];

  int b = blockIdx.x;
  int xcd = b & 7, kk_ = b >> 3;
  int gn = xcd + 8*(kk_ >> 3), pair = kk_ & 7;
  int g = gn >> 3, n = gn & 7;

  const u16* Q  = qb  + (size_t)g*MROWS*EMB + (size_t)n*SEQ*EMB;
  const u16* Kp = kb  + (size_t)g*MROWS*EMB + (size_t)n*SEQ*EMB;
  const u16* Vt = vtb + (size_t)g*EMB*MROWS + (size_t)n*SEQ;
  u16* H = hb + (size_t)(n*SEQ)*ldh + (size_t)g*EMB;

  int tid = threadIdx.x;
  int w = tid >> 6, l = tid & 63;
  int qg = w >> 1;
  int cg = w & 1;
  int frow = l & 15;
  int fsw = frow & 7;
  int srow = tid >> 3;
  int sphys = tid & 7;
  int scol = ((sphys ^ (srow & 7)) << 3);

#define KSTAGE(base, pc, buf) do { \
    gload16((base) + (pc)*128,      kls + (buf)*8192 + w*512); \
    gload16((base) + (pc)*128 + 64, kls + (buf)*8192 + 4096 + w*512); \
  } while(0)
#define VSTAGE(vc, buf) do { \
    gload16(Vs + (size_t)((vc)*128)*MROWS,      vls + (buf)*8192 + w*512); \
    gload16(Vs + (size_t)((vc)*128 + 64)*MROWS, vls + (buf)*8192 + 4096 + w*512); \
  } while(0)

  for (int half = 0; half < 2; ++half) {
    int qt = half ? 15 - pair : pair;
    int q0 = qt * 64;
    int nt = qt + 1;

    f32x4 acc[6][4];
    #pragma unroll
    for (int i = 0; i < 6; ++i)
      #pragma unroll
      for (int j = 0; j < 4; ++j) acc[i][j] = (f32x4)0.0f;
    float m_reg = -1e30f, l_reg = 0.f;

    const u16* Qs = Q + (size_t)(q0 + srow)*EMB + scol;
    bf16x8 qreg[12][2];
    KSTAGE(Qs, 0, 0);
    KSTAGE(Qs, 1, 1);
    VMCNT2; BARRIER;
    #pragma unroll
    for (int pc = 0; pc < 6; ++pc) {
      if (pc < 4) KSTAGE(Qs, pc+2, (pc+2)%3);
      const u16* qb_ = kls + (pc%3)*8192;
      #pragma unroll
      for (int kk2 = 0; kk2 < 2; ++kk2)
        #pragma unroll
        for (int kkl = 0; kkl < 2; ++kkl)
          qreg[2*pc + kk2][kkl] = *(const bf16x8*)(qb_ + kk2*4096 + (qg*16 + frow)*64
                                                   + (((kkl*4 + (l>>4)) ^ fsw) << 3));
      if (pc < 4) { VMCNT2; } else if (pc == 4) { VMCNT0; }
      LGKM0; BARRIER;
    }

    for (int tt = 0; tt < nt; ++tt) {
      int t0 = tt*64;
      const u16* Ks = Kp + (size_t)(t0 + srow)*EMB + scol;
      const u16* Vs = Vt + (size_t)srow*MROWS + t0 + scol;
      if (tt == 0) { KSTAGE(Ks, 0, 0); KSTAGE(Ks, 1, 1); }
      VMCNT2; BARRIER;

      f32x4 sacc[2]; sacc[0] = (f32x4)0.0f; sacc[1] = (f32x4)0.0f;
      #pragma unroll
      for (int c = 0; c < 6; ++c) {
        if (c < 4)       KSTAGE(Ks, c+2, (c+2)%3);
        else if (c == 4) VSTAGE(0, 0);
        else             VSTAGE(1, 1);
        const u16* kb_ = kls + (c%3)*8192;
        __builtin_amdgcn_s_setprio(1);
        #pragma unroll
        for (int kk2 = 0; kk2 < 2; ++kk2) {
          #pragma unroll
          for (int kkl = 0; kkl < 2; ++kkl) {
            int so = ((kkl*4 + (l>>4)) ^ fsw) << 3;
            bf16x8 aq = qreg[2*c + kk2][kkl];
            #pragma unroll
            for (int cc = 0; cc < 2; ++cc) {
              bf16x8 bk_ = *(const bf16x8*)(kb_ + kk2*4096 + ((cg*2 + cc)*16 + frow)*64 + so);
              sacc[cc] = __builtin_amdgcn_mfma_f32_16x16x32_bf16(aq, bk_, sacc[cc], 0, 0, 0);
            }
          }
        }
        __builtin_amdgcn_s_setprio(0);
        if (c < 5) { VMCNT2; LGKM0; BARRIER; }
      }

      #pragma unroll
      for (int cc = 0; cc < 2; ++cc)
        #pragma unroll
        for (int r = 0; r < 4; ++r)
          s_t[(qg*16 + (l>>4)*4 + r)*68 + cg*32 + cc*16 + (l&15)] = sacc[cc][r]*SCALE_S;
      LGKM0; BARRIER;
      {
        int qglob = q0 + srow;
        int cbase = t0 + sphys*8;
        float v[8]; float mx = -1e30f;
        #pragma unroll
        for (int j = 0; j < 8; ++j) {
          float s = s_t[srow*68 + sphys*8 + j];
          if (cbase + j > qglob) s = -1e30f;
          v[j] = s; mx = fmaxf(mx, s);
        }
        mx = fmaxf(mx, __shfl_xor(mx, 1));
        mx = fmaxf(mx, __shfl_xor(mx, 2));
        mx = fmaxf(mx, __shfl_xor(mx, 4));
        float mn = fmaxf(m_reg, mx);
        float esc = __expf(m_reg - mn);
        float ps = 0.f; u16 pk[8];
        #pragma unroll
        for (int j = 0; j < 8; ++j) { float p = __expf(v[j] - mn); ps += p; pk[j] = f2bf(p); }
        ps += __shfl_xor(ps, 1); ps += __shfl_xor(ps, 2); ps += __shfl_xor(ps, 4);
        l_reg = l_reg*esc + ps; m_reg = mn;
        if (sphys == 0) e_s[srow] = esc;
        uint4 pv;
        pv.x = (uint32_t)pk[0] | ((uint32_t)pk[1] << 16);
        pv.y = (uint32_t)pk[2] | ((uint32_t)pk[3] << 16);
        pv.z = (uint32_t)pk[4] | ((uint32_t)pk[5] << 16);
        pv.w = (uint32_t)pk[6] | ((uint32_t)pk[7] << 16);
        *(uint4*)(p_t + srow*64 + ((sphys ^ (srow & 7)) << 3)) = pv;
      }
      VMCNT2; LGKM0; BARRIER;
      float er[4];
      #pragma unroll
      for (int r = 0; r < 4; ++r) er[r] = e_s[qg*16 + (l>>4)*4 + r];
      #pragma unroll
      for (int i = 0; i < 6; ++i)
        #pragma unroll
        for (int j = 0; j < 4; ++j)
          #pragma unroll
          for (int r = 0; r < 4; ++r) acc[i][j][r] *= er[r];
      bf16x8 pa[2];
      #pragma unroll
      for (int kk = 0; kk < 2; ++kk)
        pa[kk] = *(const bf16x8*)(p_t + (qg*16 + frow)*64 + (((kk*4 + (l>>4)) ^ fsw) << 3));
      bool stage_next = (tt + 1 < nt);
      const u16* Ks2 = Kp + (size_t)(t0 + 64 + srow)*EMB + scol;
      #pragma unroll
      for (int c = 0; c < 6; ++c) {
        if (c < 4)            VSTAGE(c+2, (c+2)%3);
        else if (stage_next)  { if (c == 4) KSTAGE(Ks2, 0, 0); else KSTAGE(Ks2, 1, 1); }
        const u16* vb_ = vls + (c%3)*8192;
        __builtin_amdgcn_s_setprio(1);
        #pragma unroll
        for (int cf = 0; cf < 4; ++cf) {
          #pragma unroll
          for (int kk = 0; kk < 2; ++kk) {
            bf16x8 vbf = *(const bf16x8*)(vb_ + (cg*64 + cf*16 + frow)*64 + (((kk*4 + (l>>4)) ^ fsw) << 3));
            acc[c][cf] = __builtin_amdgcn_mfma_f32_16x16x32_bf16(pa[kk], vbf, acc[c][cf], 0, 0, 0);
          }
        }
        __builtin_amdgcn_s_setprio(0);
        if (c < 4)      { VMCNT2; LGKM0; BARRIER; }
        else if (c == 4){ if (stage_next) { VMCNT2; } else { VMCNT0; } LGKM0; BARRIER; }
      }
    } // tt
    if (sphys == 0) e_s[srow] = l_reg;
    LGKM0; BARRIER;
    float linv[4];
    #pragma unroll
    for (int r = 0; r < 4; ++r) linv[r] = 1.0f / e_s[qg*16 + (l>>4)*4 + r];
    #pragma unroll
    for (int i = 0; i < 6; ++i)
      #pragma unroll
      for (int j = 0; j < 4; ++j) {
        int col = i*128 + cg*64 + j*16 + (l & 15);
        #pragma unroll
        for (int r = 0; r < 4; ++r) {
          int row = q0 + qg*16 + (l>>4)*4 + r;
          H[(size_t)row*ldh + col] = f2bf(acc[i][j][r]*linv[r]);
        }
      }
    BARRIER;
  } // half
#undef KSTAGE
#undef VSTAGE
}

// ---------------- host ----------------
extern "C" void kernel_launch(void* const* d_in, const int* in_sizes, int n_in,
                              void* d_out, int out_size, void* d_ws, size_t ws_size,
                              hipStream_t stream) {
  const float* x  = (const float*)d_in[0];
  const float* Wq = (const float*)d_in[1];
  const float* bq = (const float*)d_in[2];
  const float* Wk = (const float*)d_in[3];
  const float* bk = (const float*)d_in[4];
  const float* Wv = (const float*)d_in[5];
  const float* bv = (const float*)d_in[6];
  const float* Wc = (const float*)d_in[7];
  const float* bc = (const float*)d_in[8];
  float* out = (float*)d_out;

  const size_t XB  = (size_t)MROWS*EMB*sizeof(u16);
  const size_t WHB = (size_t)EMB*EMB*sizeof(u16);
  const size_t per_g = 4*WHB + 4*XB;
  long long avail = (long long)ws_size - (long long)XB - 4096;
  int G = (int)(avail / (long long)per_g);
  if (G < 1) G = 1;
  if (G > NHEAD) G = NHEAD;

  char* ws = (char*)d_ws;
  u16* xb  = (u16*)ws;  ws += XB;
  u16* wqb = (u16*)ws;  ws += (size_t)(2*G)*WHB;
  u16* wvb = (u16*)ws;  ws += (size_t)G*WHB;
  u16* wcb = (u16*)ws;  ws += (size_t)G*WHB;
  u16* qb  = (u16*)ws;  ws += (size_t)(2*G)*XB;
  u16* vtb = (u16*)ws;  ws += (size_t)G*XB;
  u16* hbf = (u16*)ws;  ws += (size_t)G*XB;

  k_cvt<<<dim3(3072), dim3(256), 0, stream>>>(x, xb, (long)MROWS*EMB);

  for (int h0 = 0; h0 < NHEAD; h0 += G) {
    int Gi = (G < NHEAD - h0) ? G : (NHEAD - h0);
    long nw = (long)Gi*EMB*EMB;
    k_cvt3<<<dim3((unsigned)(nw/8/256), 1, 3), dim3(256), 0, stream>>>(
        Wq + (size_t)h0*EMB*EMB, Wk + (size_t)h0*EMB*EMB, Wv + (size_t)h0*EMB*EMB,
        wqb, wqb + (size_t)Gi*EMB*EMB, wvb, nw);
    k_cvtwc<<<dim3((unsigned)((768L*Gi*EMB/4)/256)), dim3(256), 0, stream>>>(Wc, wcb, Gi, h0);
    // fused Q|K projection: C[8192, 2*Gi*768] sliced into qb (q slices then k slices)
    k_gemm256<<<dim3(32, 12*Gi), dim3(512), 0, stream>>>(
        xb, EMB, wqb, EMB, EMB,
        qb, (long)MROWS*EMB, 768,
        bq + (size_t)h0*EMB, bk + (size_t)h0*EMB, Gi, 0);
    // Vt = Wv*x^T + bv: C[Gi*768, 8192], row bias
    k_gemm256<<<dim3(3*Gi, 64), dim3(512), 0, stream>>>(
        wvb, EMB, xb, EMB, EMB,
        vtb, 0L, MROWS,
        bv + (size_t)h0*EMB, (const float*)0, 9999, 1);
    // flash attention -> hbf [8192, Gi*768]
    k_attn<<<dim3(8*NBAT*Gi), dim3(512), 0, stream>>>(
        qb, qb + (size_t)Gi*MROWS*EMB, vtb, hbf, Gi*EMB);
    // out += heads_group * Wc_group^T (+bc on first group)
    k_gemm<<<dim3(64, 6, 1), dim3(256), 0, stream>>>(
        hbf, 0L, Gi*EMB, wcb, 0L, Gi*EMB, Gi*EMB,
        (u16*)0, out, 0L, EMB,
        (h0 == 0 ? bc : (const float*)0), (const float*)0, 0L, 9999,
        (h0 == 0 ? 2 : 3), 0);
  }
}